// Round 1
// baseline (917.242 us; speedup 1.0000x reference)
//
#include <hip/hip_runtime.h>
#include <math.h>

#define IMG 128
#define PATCH 16
#define L 64
#define D 256
#define DIN 512
#define DH 64
#define H 8
#define NSTATE 64
#define DCONV 4
#define DEPTH 2
#define NCLS 1000
#define BATCH 16
#define DINPROJ 1160   // 2*DIN + 2*N + H
#define CDIM 640       // DIN + 2*N
#define EPS 1e-6f

__device__ __forceinline__ int snake_tok(int s){
    int r = s >> 3, c = s & 7;
    return (r & 1) ? (r * 8 + (7 - c)) : (r * 8 + c);
}
__device__ __forceinline__ float silu_f(float x){ return x / (1.f + expf(-x)); }
__device__ __forceinline__ float softplus_f(float x){ return x > 20.f ? x : log1pf(expf(x)); }

__device__ __forceinline__ float block_sum256(float v){
    __shared__ float sm[4];
    #pragma unroll
    for (int o = 32; o > 0; o >>= 1) v += __shfl_down(v, o);
    if ((threadIdx.x & 63) == 0) sm[threadIdx.x >> 6] = v;
    __syncthreads();
    return sm[0] + sm[1] + sm[2] + sm[3];
}

// ---------------- patchify: x (B,3,128,128) -> p (B, L(snake order), 768)
__global__ void patchify_k(const float* __restrict__ x, float* __restrict__ p){
    int s = blockIdx.x, b = blockIdx.y;
    int tok = snake_tok(s), gy = tok >> 3, gx = tok & 7;
    const float* xb = x + (size_t)b * 3 * IMG * IMG;
    float* pr = p + (size_t)(b * L + s) * 768;
    for (int idx = threadIdx.x; idx < 768; idx += blockDim.x){
        int c = idx >> 8, rem = idx & 255, py = rem >> 4, px = rem & 15;
        pr[idx] = xb[((size_t)c * IMG + gy * PATCH + py) * IMG + gx * PATCH + px];
    }
}

// ---------------- t += patch_b[d] + pos[tok(s)*D + d]
__global__ void add_bias_pos_k(float* __restrict__ t, const float* __restrict__ pb,
                               const float* __restrict__ pos){
    int i = blockIdx.x * blockDim.x + threadIdx.x;     // over B*L*D
    int d = i & (D - 1);
    int s = (i >> 8) & (L - 1);
    int tok = snake_tok(s);
    t[i] += pb[d] + pos[tok * D + d];
}

// ---------------- generic tiled fp32 GEMM: C = alpha*A@B (+bias) + beta*C
// A: M x K row-major.  B: K x N row-major (TRANSB=false) or N x K (TRANSB=true).
template<bool TRANSB>
__global__ __launch_bounds__(256) void gemm64_k(const float* __restrict__ A,
                                                const float* __restrict__ Bm,
                                                float* __restrict__ C,
                                                const float* __restrict__ bias,
                                                int M, int N, int K,
                                                float alpha, float beta){
    __shared__ float As[16][66];
    __shared__ float Bs[16][66];
    int tx = threadIdx.x & 15, ty = threadIdx.x >> 4;
    int n0 = blockIdx.x * 64, m0 = blockIdx.y * 64;
    float acc[4][4] = {};
    for (int k0 = 0; k0 < K; k0 += 16){
        {   // load A tile 64x16 (K assumed multiple of 16)
            int k = threadIdx.x & 15, m = threadIdx.x >> 4;
            #pragma unroll
            for (int r = 0; r < 4; ++r){
                int mm = m + r * 16, gm = m0 + mm;
                As[k][mm] = (gm < M) ? A[(size_t)gm * K + k0 + k] : 0.f;
            }
        }
        if (!TRANSB){
            int k = threadIdx.x >> 6, n = threadIdx.x & 63;
            int gn = n0 + n;
            #pragma unroll
            for (int r = 0; r < 4; ++r){
                int kk = k + r * 4;
                Bs[kk][n] = (gn < N) ? Bm[(size_t)(k0 + kk) * N + gn] : 0.f;
            }
        } else {
            int n = threadIdx.x >> 4, k = threadIdx.x & 15;
            #pragma unroll
            for (int r = 0; r < 4; ++r){
                int nn = n + r * 16, gn = n0 + nn;
                Bs[k][nn] = (gn < N) ? Bm[(size_t)gn * K + k0 + k] : 0.f;
            }
        }
        __syncthreads();
        #pragma unroll
        for (int k = 0; k < 16; ++k){
            float a[4], bb[4];
            #pragma unroll
            for (int i = 0; i < 4; ++i) a[i] = As[k][ty * 4 + i];
            #pragma unroll
            for (int j = 0; j < 4; ++j) bb[j] = Bs[k][tx * 4 + j];
            #pragma unroll
            for (int i = 0; i < 4; ++i)
                #pragma unroll
                for (int j = 0; j < 4; ++j)
                    acc[i][j] += a[i] * bb[j];
        }
        __syncthreads();
    }
    #pragma unroll
    for (int i = 0; i < 4; ++i){
        int gm = m0 + ty * 4 + i;
        if (gm >= M) continue;
        #pragma unroll
        for (int j = 0; j < 4; ++j){
            int gn = n0 + tx * 4 + j;
            if (gn >= N) continue;
            float v = alpha * acc[i][j];
            if (bias) v += bias[gn];
            size_t o = (size_t)gm * N + gn;
            C[o] = (beta == 0.f) ? v : fmaf(beta, C[o], v);
        }
    }
}

// ---------------- rmsnorm over D=256, one row per block
__global__ void rmsnorm256_k(const float* __restrict__ x, const float* __restrict__ w,
                             float* __restrict__ o){
    int row = blockIdx.x;
    float v = x[(size_t)row * D + threadIdx.x];
    float ss = block_sum256(v * v);
    float sc = rsqrtf(ss / (float)D + EPS);
    o[(size_t)row * D + threadIdx.x] = v * sc * w[threadIdx.x];
}

// ---------------- dt = softplus(zx[...,1152+h]+dtb); cum = cumsum(-exp(Alog)*dt)
__global__ void dt_cum_k(const float* __restrict__ zx, const float* __restrict__ dtb,
                         const float* __restrict__ Alog, float* __restrict__ dts,
                         float* __restrict__ cums, int rev){
    int i = threadIdx.x;            // b*H + h, 128 total
    if (i >= BATCH * H) return;
    int b = i >> 3, h = i & 7;
    float a = -expf(Alog[h]);
    float dtbh = dtb[h];
    float cum = 0.f;
    for (int s = 0; s < L; ++s){
        int l = rev ? (L - 1 - s) : s;
        float xr = zx[(size_t)(b * L + l) * DINPROJ + DIN + CDIM + h] + dtbh;
        float dt = softplus_f(xr);
        cum += a * dt;
        dts[(size_t)(b * L + s) * H + h] = dt;
        cums[(size_t)(b * L + s) * H + h] = cum;
    }
}

// ---------------- causal depthwise conv (in scan order) + silu
__global__ void conv_silu_k(const float* __restrict__ zx, const float* __restrict__ cw,
                            const float* __restrict__ cb, float* __restrict__ xbc, int rev){
    int s = blockIdx.x, b = blockIdx.y;
    for (int c = threadIdx.x; c < CDIM; c += blockDim.x){
        float acc = cb[c];
        #pragma unroll
        for (int k = 0; k < DCONV; ++k){
            int j = s - (DCONV - 1) + k;
            if (j >= 0){
                int l = rev ? (L - 1 - j) : j;
                acc += cw[c * DCONV + k] * zx[(size_t)(b * L + l) * DINPROJ + DIN + c];
            }
        }
        xbc[(size_t)(b * L + s) * CDIM + c] = silu_f(acc);
    }
}

// ---------------- S[b,s,j] = C[b,s,:] . B[b,j,:]   (shared across heads, G=1)
__global__ __launch_bounds__(256) void bc_dots_k(const float* __restrict__ xbc,
                                                 float* __restrict__ S){
    __shared__ float Bl[64][65];
    __shared__ float Cl[64][65];
    int b = blockIdx.x;
    for (int idx = threadIdx.x; idx < 64 * 64; idx += 256){
        int j = idx >> 6, n = idx & 63;
        Bl[j][n] = xbc[(size_t)(b * L + j) * CDIM + DIN + n];
        Cl[j][n] = xbc[(size_t)(b * L + j) * CDIM + DIN + NSTATE + n];
    }
    __syncthreads();
    for (int idx = threadIdx.x; idx < 64 * 64; idx += 256){
        int s = idx >> 6, j = idx & 63;
        float acc = 0.f;
        #pragma unroll
        for (int n = 0; n < 64; ++n) acc += Cl[s][n] * Bl[j][n];
        S[((size_t)b * L + s) * L + j] = acc;
    }
}

// ---------------- Y[b,pos(s),h,:] = sum_{j<=s} S*exp(cum[s]-cum[j])*dt[j]*xs[j] + Dp*xs[s]
__global__ __launch_bounds__(256) void yscan_k(const float* __restrict__ S,
                                               const float* __restrict__ xbc,
                                               const float* __restrict__ dts,
                                               const float* __restrict__ cums,
                                               const float* __restrict__ Dp,
                                               float* __restrict__ y, int rev){
    __shared__ float Am[64][65];
    __shared__ float Xs[64][65];
    __shared__ float cumS[64], dtS[64];
    int h = blockIdx.x, b = blockIdx.y;
    if (threadIdx.x < 64){
        cumS[threadIdx.x] = cums[(size_t)(b * L + threadIdx.x) * H + h];
        dtS[threadIdx.x]  = dts[(size_t)(b * L + threadIdx.x) * H + h];
    }
    for (int idx = threadIdx.x; idx < 64 * 64; idx += 256){
        int j = idx >> 6, pcol = idx & 63;
        Xs[j][pcol] = xbc[(size_t)(b * L + j) * CDIM + h * DH + pcol];
        Am[j][pcol] = S[((size_t)b * L + j) * L + pcol];  // Am[s][j] raw
    }
    __syncthreads();
    for (int idx = threadIdx.x; idx < 64 * 64; idx += 256){
        int s = idx >> 6, j = idx & 63;
        float v = 0.f;
        if (j <= s) v = Am[s][j] * expf(cumS[s] - cumS[j]) * dtS[j];
        Am[s][j] = v;
    }
    __syncthreads();
    float dp = Dp[h];
    for (int idx = threadIdx.x; idx < 64 * 64; idx += 256){
        int s = idx >> 6, pcol = idx & 63;
        float acc = dp * Xs[s][pcol];
        #pragma unroll
        for (int j = 0; j < 64; ++j) acc += Am[s][j] * Xs[j][pcol];
        int l = rev ? (L - 1 - s) : s;
        y[(size_t)(b * L + l) * DIN + h * DH + pcol] = acc;
    }
}

// ---------------- y = rmsnorm(y * silu(z), gn)   in-place, row width 512
__global__ void gate_rmsnorm_k(float* __restrict__ y, const float* __restrict__ zx,
                               const float* __restrict__ gn){
    int row = blockIdx.x;   // b*L + l
    float g[2]; float ss = 0.f;
    #pragma unroll
    for (int r = 0; r < 2; ++r){
        int c = threadIdx.x + 256 * r;
        float z = zx[(size_t)row * DINPROJ + c];
        float val = y[(size_t)row * DIN + c] * silu_f(z);
        g[r] = val; ss += val * val;
    }
    float tot = block_sum256(ss);
    float sc = rsqrtf(tot / (float)DIN + EPS);
    #pragma unroll
    for (int r = 0; r < 2; ++r){
        int c = threadIdx.x + 256 * r;
        y[(size_t)row * DIN + c] = g[r] * sc * gn[c];
    }
}

// ---------------- tm[b,d] = mean_l r[b,l,d]
__global__ void mean_l_k(const float* __restrict__ r, float* __restrict__ tm){
    int b = blockIdx.x, d = threadIdx.x;
    float acc = 0.f;
    for (int l = 0; l < L; ++l) acc += r[(size_t)(b * L + l) * D + d];
    tm[b * D + d] = acc * (1.f / (float)L);
}

extern "C" void kernel_launch(void* const* d_in, const int* in_sizes, int n_in,
                              void* d_out, int out_size, void* d_ws, size_t ws_size,
                              hipStream_t stream){
    (void)in_sizes; (void)n_in; (void)out_size; (void)ws_size;
    const float* x       = (const float*)d_in[0];
    const float* patch_w = (const float*)d_in[1];
    const float* patch_b = (const float*)d_in[2];
    const float* pos     = (const float*)d_in[3];
    const float* norms_w = (const float*)d_in[4];
    const float* final_w = (const float*)d_in[5];
    const float* head_w  = (const float*)d_in[6];
    const float* head_b  = (const float*)d_in[7];
    const float* Win[2]  = {(const float*)d_in[8],  (const float*)d_in[16]};
    const float* cw[2]   = {(const float*)d_in[9],  (const float*)d_in[17]};
    const float* cb[2]   = {(const float*)d_in[10], (const float*)d_in[18]};
    const float* dtb[2]  = {(const float*)d_in[11], (const float*)d_in[19]};
    const float* Alog[2] = {(const float*)d_in[12], (const float*)d_in[20]};
    const float* Dp[2]   = {(const float*)d_in[13], (const float*)d_in[21]};
    const float* gn[2]   = {(const float*)d_in[14], (const float*)d_in[22]};
    const float* Wout[2] = {(const float*)d_in[15], (const float*)d_in[23]};

    float* ws  = (float*)d_ws;
    float* p    = ws;                 // B*L*768      = 786432
    float* t    = p    + 786432;      // B*L*D        = 262144
    float* nx   = t    + 262144;      // B*L*D        = 262144
    float* tm   = nx   + 262144;      // B*D          = 4096
    float* zx0  = tm   + 4096;        // B*L*DINPROJ  = 1187840
    float* zx1  = zx0  + 1187840;
    float* xbc0 = zx1  + 1187840;     // B*L*CDIM     = 655360
    float* xbc1 = xbc0 + 655360;
    float* dts0 = xbc1 + 655360;      // B*L*H        = 8192
    float* dts1 = dts0 + 8192;
    float* cum0 = dts1 + 8192;
    float* cum1 = cum0 + 8192;
    float* S0   = cum1 + 8192;        // B*L*L        = 65536
    float* S1   = S0   + 65536;
    float* y0   = S1   + 65536;       // B*L*DIN      = 524288
    float* y1   = y0   + 524288;
    float* zx[2]  = {zx0, zx1};
    float* xbc[2] = {xbc0, xbc1};
    float* dts[2] = {dts0, dts1};
    float* cums[2]= {cum0, cum1};
    float* Sm[2]  = {S0, S1};
    float* yb[2]  = {y0, y1};

    const int BL = BATCH * L;   // 1024 rows

    // --- patch embedding (snake-ordered) ---
    patchify_k<<<dim3(L, BATCH), 256, 0, stream>>>(x, p);
    gemm64_k<true><<<dim3(D / 64, BL / 64), 256, 0, stream>>>(
        p, patch_w, t, nullptr, BL, D, 768, 1.f, 0.f);
    add_bias_pos_k<<<BL, 256, 0, stream>>>(t, patch_b, pos);

    // --- layers ---
    for (int i = 0; i < DEPTH; ++i){
        rmsnorm256_k<<<BL, 256, 0, stream>>>(t, norms_w + i * D, nx);
        for (int dir = 0; dir < 2; ++dir){
            const float* Wi  = Win[dir]  + (size_t)i * D * DINPROJ;
            const float* cwi = cw[dir]   + (size_t)i * CDIM * DCONV;
            const float* cbi = cb[dir]   + (size_t)i * CDIM;
            const float* dtbi= dtb[dir]  + (size_t)i * H;
            const float* Ali = Alog[dir] + (size_t)i * H;
            const float* Dpi = Dp[dir]   + (size_t)i * H;
            const float* gni = gn[dir]   + (size_t)i * DIN;
            const float* Woi = Wout[dir] + (size_t)i * DIN * D;

            gemm64_k<false><<<dim3((DINPROJ + 63) / 64, BL / 64), 256, 0, stream>>>(
                nx, Wi, zx[dir], nullptr, BL, DINPROJ, D, 1.f, 0.f);
            dt_cum_k<<<1, 128, 0, stream>>>(zx[dir], dtbi, Ali, dts[dir], cums[dir], dir);
            conv_silu_k<<<dim3(L, BATCH), 256, 0, stream>>>(zx[dir], cwi, cbi, xbc[dir], dir);
            bc_dots_k<<<BATCH, 256, 0, stream>>>(xbc[dir], Sm[dir]);
            yscan_k<<<dim3(H, BATCH), 256, 0, stream>>>(
                Sm[dir], xbc[dir], dts[dir], cums[dir], Dpi, yb[dir], dir);
            gate_rmsnorm_k<<<BL, 256, 0, stream>>>(yb[dir], zx[dir], gni);
            gemm64_k<false><<<dim3(D / 64, BL / 64), 256, 0, stream>>>(
                yb[dir], Woi, t, nullptr, BL, D, DIN, 0.5f, 1.f);
        }
    }

    // --- head ---
    rmsnorm256_k<<<BL, 256, 0, stream>>>(t, final_w, nx);
    mean_l_k<<<BATCH, 256, 0, stream>>>(nx, tm);
    gemm64_k<false><<<dim3((NCLS + 63) / 64, 1), 256, 0, stream>>>(
        tm, head_w, (float*)d_out, head_b, BATCH, NCLS, D, 1.f, 0.f);
}

// Round 2
// 433.611 us; speedup vs baseline: 2.1154x; 2.1154x over previous
//
#include <hip/hip_runtime.h>
#include <math.h>

#define IMG 128
#define PATCH 16
#define L 64
#define D 256
#define DIN 512
#define DH 64
#define H 8
#define NSTATE 64
#define DCONV 4
#define DEPTH 2
#define NCLS 1000
#define BATCH 16
#define DINPROJ 1160   // 2*DIN + 2*N + H
#define CDIM 640       // DIN + 2*N
#define EPS 1e-6f

__device__ __forceinline__ int snake_tok(int s){
    int r = s >> 3, c = s & 7;
    return (r & 1) ? (r * 8 + (7 - c)) : (r * 8 + c);
}
__device__ __forceinline__ float silu_f(float x){ return x / (1.f + expf(-x)); }
__device__ __forceinline__ float softplus_f(float x){ return x > 20.f ? x : log1pf(expf(x)); }

__device__ __forceinline__ float block_sum256(float v){
    __shared__ float sm[4];
    #pragma unroll
    for (int o = 32; o > 0; o >>= 1) v += __shfl_down(v, o);
    if ((threadIdx.x & 63) == 0) sm[threadIdx.x >> 6] = v;
    __syncthreads();
    return sm[0] + sm[1] + sm[2] + sm[3];
}

// ---------------- patchify: x (B,3,128,128) -> p (B, L(snake order), 768)
__global__ void patchify_k(const float* __restrict__ x, float* __restrict__ p){
    int s = blockIdx.x, b = blockIdx.y;
    int tok = snake_tok(s), gy = tok >> 3, gx = tok & 7;
    const float* xb = x + (size_t)b * 3 * IMG * IMG;
    float* pr = p + (size_t)(b * L + s) * 768;
    for (int idx = threadIdx.x; idx < 768; idx += blockDim.x){
        int c = idx >> 8, rem = idx & 255, py = rem >> 4, px = rem & 15;
        pr[idx] = xb[((size_t)c * IMG + gy * PATCH + py) * IMG + gx * PATCH + px];
    }
}

// ---------------- double-buffered fp32 GEMM, 64x64 tile, BK=32, 4x4/thread.
// blockIdx.z encodes (dir, split): dir = z/splitk, split = z%splitk.
// C (per dir) points at splitk consecutive MxN slabs (raw partial sums).
template<bool TRANSB>
__global__ __launch_bounds__(256, 2) void gemm_dbuf_k(
    const float* __restrict__ A0, const float* __restrict__ A1,
    const float* __restrict__ Bm0, const float* __restrict__ Bm1,
    float* __restrict__ C0, float* __restrict__ C1,
    int M, int N, int K, int splitk)
{
    __shared__ float As[2][32][68];
    __shared__ float Bs[2][32][64];
    const int z = blockIdx.z;
    const int dir = z / splitk, split = z - dir * splitk;
    const float* __restrict__ A  = dir ? A1 : A0;
    const float* __restrict__ Bm = dir ? Bm1 : Bm0;
    float* __restrict__ C = (dir ? C1 : C0) + (size_t)split * M * N;
    const int Ks = K / splitk;
    const int kbase = split * Ks;
    const int t = threadIdx.x;
    const int tx = t & 15, ty = t >> 4;
    const int n0 = blockIdx.x * 64, m0 = blockIdx.y * 64;

    const int am0 = t >> 3;                     // A: row within tile (+r*32)
    const int ak4 = (t & 7) * 4;                // A: k within tile (float4)
    const int bkn = TRANSB ? (t >> 3) : (t >> 4);
    const int bof = TRANSB ? ((t & 7) * 4) : ((t & 15) * 4);

    float ar[2][4], br[2][4];

    auto loadTile = [&](int kk){
        #pragma unroll
        for (int r = 0; r < 2; ++r){
            int gm = m0 + am0 + r * 32;
            if (gm < M){
                const float4 v = *(const float4*)(A + (size_t)gm * K + kk + ak4);
                ar[r][0] = v.x; ar[r][1] = v.y; ar[r][2] = v.z; ar[r][3] = v.w;
            } else { ar[r][0] = ar[r][1] = ar[r][2] = ar[r][3] = 0.f; }
        }
        if (TRANSB){
            #pragma unroll
            for (int r = 0; r < 2; ++r){
                int gn = n0 + bkn + r * 32;
                if (gn < N){
                    const float4 v = *(const float4*)(Bm + (size_t)gn * K + kk + bof);
                    br[r][0] = v.x; br[r][1] = v.y; br[r][2] = v.z; br[r][3] = v.w;
                } else { br[r][0] = br[r][1] = br[r][2] = br[r][3] = 0.f; }
            }
        } else {
            #pragma unroll
            for (int r = 0; r < 2; ++r){
                int gk = kk + bkn + r * 16;
                int gn = n0 + bof;
                const float* src = Bm + (size_t)gk * N + gn;
                if (gn + 3 < N){
                    const float4 v = *(const float4*)src;
                    br[r][0] = v.x; br[r][1] = v.y; br[r][2] = v.z; br[r][3] = v.w;
                } else {
                    #pragma unroll
                    for (int i = 0; i < 4; ++i) br[r][i] = (gn + i < N) ? src[i] : 0.f;
                }
            }
        }
    };
    auto storeTile = [&](int buf){
        #pragma unroll
        for (int r = 0; r < 2; ++r)
            #pragma unroll
            for (int i = 0; i < 4; ++i)
                As[buf][ak4 + i][am0 + r * 32] = ar[r][i];
        if (TRANSB){
            #pragma unroll
            for (int r = 0; r < 2; ++r)
                #pragma unroll
                for (int i = 0; i < 4; ++i)
                    Bs[buf][bof + i][bkn + r * 32] = br[r][i];
        } else {
            #pragma unroll
            for (int r = 0; r < 2; ++r)
                *(float4*)&Bs[buf][bkn + r * 16][bof] =
                    make_float4(br[r][0], br[r][1], br[r][2], br[r][3]);
        }
    };

    float acc[4][4] = {};
    auto compute = [&](int buf){
        #pragma unroll
        for (int k = 0; k < 32; ++k){
            const float4 a = *(const float4*)&As[buf][k][ty * 4];
            const float4 b = *(const float4*)&Bs[buf][k][tx * 4];
            const float av[4] = {a.x, a.y, a.z, a.w};
            const float bv[4] = {b.x, b.y, b.z, b.w};
            #pragma unroll
            for (int i = 0; i < 4; ++i)
                #pragma unroll
                for (int j = 0; j < 4; ++j)
                    acc[i][j] = fmaf(av[i], bv[j], acc[i][j]);
        }
    };

    const int nk = Ks / 32;
    loadTile(kbase);
    storeTile(0);
    __syncthreads();
    for (int kt = 0; kt < nk; ++kt){
        const int cur = kt & 1;
        if (kt + 1 < nk) loadTile(kbase + (kt + 1) * 32);
        compute(cur);
        if (kt + 1 < nk){
            storeTile(cur ^ 1);
            __syncthreads();
        }
    }

    #pragma unroll
    for (int i = 0; i < 4; ++i){
        int gm = m0 + ty * 4 + i;
        if (gm >= M) continue;
        float* crow = C + (size_t)gm * N;
        int gn = n0 + tx * 4;
        if (gn + 3 < N){
            *(float4*)&crow[gn] = make_float4(acc[i][0], acc[i][1], acc[i][2], acc[i][3]);
        } else {
            #pragma unroll
            for (int j = 0; j < 4; ++j) if (gn + j < N) crow[gn + j] = acc[i][j];
        }
    }
}

// ---------------- reduce kernels for split-K partials
__global__ void patch_red_k(const float* __restrict__ part, const float* __restrict__ pb,
                            const float* __restrict__ pos, float* __restrict__ t){
    int i = blockIdx.x * 256 + threadIdx.x;      // B*L*D
    int d = i & (D - 1), s = (i >> 8) & (L - 1);
    float v = part[i] + part[i + 262144] + part[i + 524288] + part[i + 786432];
    t[i] = v + pb[d] + pos[snake_tok(s) * D + d];
}

__global__ void out_red_k(const float* __restrict__ part, float* __restrict__ t){
    int i = blockIdx.x * 256 + threadIdx.x;      // B*L*D
    t[i] += 0.5f * (part[i] + part[i + 262144] + part[i + 524288] + part[i + 786432]);
}

__global__ void head_red_k(const float* __restrict__ part, const float* __restrict__ hb,
                           float* __restrict__ out){
    int i = blockIdx.x * 256 + threadIdx.x;      // 16*1000
    if (i >= BATCH * NCLS) return;
    float v = 0.f;
    #pragma unroll
    for (int s2 = 0; s2 < 8; ++s2) v += part[s2 * (BATCH * NCLS) + i];
    out[i] = v + hb[i % NCLS];
}

// ---------------- dt = softplus(...); cum = inclusive scan of -exp(Alog)*dt
// one wave per (b,h); 4 waves/block; grid (32, 2dirs)
__global__ void dt_scan_k(const float* __restrict__ zx0, const float* __restrict__ zx1,
                          const float* __restrict__ dtb0, const float* __restrict__ dtb1,
                          const float* __restrict__ Al0, const float* __restrict__ Al1,
                          float* __restrict__ dts0, float* __restrict__ dts1,
                          float* __restrict__ cums0, float* __restrict__ cums1){
    int dir = blockIdx.y;
    const float* zx  = dir ? zx1  : zx0;
    const float* dtb = dir ? dtb1 : dtb0;
    const float* Al  = dir ? Al1  : Al0;
    float* dts  = dir ? dts1  : dts0;
    float* cums = dir ? cums1 : cums0;
    int wave = threadIdx.x >> 6, lane = threadIdx.x & 63;
    int bh = blockIdx.x * 4 + wave;              // 0..127
    int b = bh >> 3, h = bh & 7;
    int s = lane;
    int l = dir ? (L - 1 - s) : s;
    float xr = zx[(size_t)(b * L + l) * DINPROJ + DIN + CDIM + h] + dtb[h];
    float dt = softplus_f(xr);
    float val = -expf(Al[h]) * dt;
    #pragma unroll
    for (int o = 1; o < 64; o <<= 1){
        float u = __shfl_up(val, o);
        if (lane >= o) val += u;
    }
    dts[(size_t)(b * L + s) * H + h]  = dt;
    cums[(size_t)(b * L + s) * H + h] = val;
}

// ---------------- causal depthwise conv (scan order) + silu; grid (L,B,2)
__global__ void conv_silu_k(const float* __restrict__ zx0, const float* __restrict__ zx1,
                            const float* __restrict__ cw0, const float* __restrict__ cw1,
                            const float* __restrict__ cb0, const float* __restrict__ cb1,
                            float* __restrict__ xbc0, float* __restrict__ xbc1){
    int dir = blockIdx.z;
    const float* zx = dir ? zx1 : zx0;
    const float* cw = dir ? cw1 : cw0;
    const float* cb = dir ? cb1 : cb0;
    float* xbc = dir ? xbc1 : xbc0;
    int s = blockIdx.x, b = blockIdx.y;
    for (int c = threadIdx.x; c < CDIM; c += blockDim.x){
        float acc = cb[c];
        #pragma unroll
        for (int k = 0; k < DCONV; ++k){
            int j = s - (DCONV - 1) + k;
            if (j >= 0){
                int l = dir ? (L - 1 - j) : j;
                acc += cw[c * DCONV + k] * zx[(size_t)(b * L + l) * DINPROJ + DIN + c];
            }
        }
        xbc[(size_t)(b * L + s) * CDIM + c] = silu_f(acc);
    }
}

// ---------------- S[b,s,j] = C[b,s,:] . B[b,j,:]; grid (B, 2)
__global__ __launch_bounds__(256) void bc_dots_k(const float* __restrict__ xbc0,
                                                 const float* __restrict__ xbc1,
                                                 float* __restrict__ S0,
                                                 float* __restrict__ S1){
    int dir = blockIdx.y;
    const float* xbc = dir ? xbc1 : xbc0;
    float* S = dir ? S1 : S0;
    __shared__ float Bl[64][65];
    __shared__ float Cl[64][65];
    int b = blockIdx.x;
    for (int idx = threadIdx.x; idx < 64 * 64; idx += 256){
        int j = idx >> 6, n = idx & 63;
        Bl[j][n] = xbc[(size_t)(b * L + j) * CDIM + DIN + n];
        Cl[j][n] = xbc[(size_t)(b * L + j) * CDIM + DIN + NSTATE + n];
    }
    __syncthreads();
    for (int idx = threadIdx.x; idx < 64 * 64; idx += 256){
        int s = idx >> 6, j = idx & 63;
        float acc = 0.f;
        #pragma unroll
        for (int n = 0; n < 64; ++n) acc += Cl[s][n] * Bl[j][n];
        S[((size_t)b * L + s) * L + j] = acc;
    }
}

// ---------------- Y; grid (H, B, 2)
__global__ __launch_bounds__(256) void yscan_k(const float* __restrict__ S0,
                                               const float* __restrict__ S1,
                                               const float* __restrict__ xbc0,
                                               const float* __restrict__ xbc1,
                                               const float* __restrict__ dts0,
                                               const float* __restrict__ dts1,
                                               const float* __restrict__ cums0,
                                               const float* __restrict__ cums1,
                                               const float* __restrict__ Dp0,
                                               const float* __restrict__ Dp1,
                                               float* __restrict__ y0,
                                               float* __restrict__ y1){
    int dir = blockIdx.z;
    const float* S = dir ? S1 : S0;
    const float* xbc = dir ? xbc1 : xbc0;
    const float* dts = dir ? dts1 : dts0;
    const float* cums = dir ? cums1 : cums0;
    const float* Dp = dir ? Dp1 : Dp0;
    float* y = dir ? y1 : y0;
    __shared__ float Am[64][65];
    __shared__ float Xs[64][65];
    __shared__ float cumS[64], dtS[64];
    int h = blockIdx.x, b = blockIdx.y;
    if (threadIdx.x < 64){
        cumS[threadIdx.x] = cums[(size_t)(b * L + threadIdx.x) * H + h];
        dtS[threadIdx.x]  = dts[(size_t)(b * L + threadIdx.x) * H + h];
    }
    for (int idx = threadIdx.x; idx < 64 * 64; idx += 256){
        int j = idx >> 6, pcol = idx & 63;
        Xs[j][pcol] = xbc[(size_t)(b * L + j) * CDIM + h * DH + pcol];
        Am[j][pcol] = S[((size_t)b * L + j) * L + pcol];
    }
    __syncthreads();
    for (int idx = threadIdx.x; idx < 64 * 64; idx += 256){
        int s = idx >> 6, j = idx & 63;
        float v = 0.f;
        if (j <= s) v = Am[s][j] * expf(cumS[s] - cumS[j]) * dtS[j];
        Am[s][j] = v;
    }
    __syncthreads();
    float dp = Dp[h];
    for (int idx = threadIdx.x; idx < 64 * 64; idx += 256){
        int s = idx >> 6, pcol = idx & 63;
        float acc = dp * Xs[s][pcol];
        #pragma unroll
        for (int j = 0; j < 64; ++j) acc += Am[s][j] * Xs[j][pcol];
        int l = dir ? (L - 1 - s) : s;
        y[(size_t)(b * L + l) * DIN + h * DH + pcol] = acc;
    }
}

// ---------------- y = rmsnorm(y * silu(z), gn); grid (BL, 2)
__global__ void gate_rmsnorm_k(float* __restrict__ y0, float* __restrict__ y1,
                               const float* __restrict__ zx0, const float* __restrict__ zx1,
                               const float* __restrict__ gn0, const float* __restrict__ gn1){
    int dir = blockIdx.y;
    float* y = dir ? y1 : y0;
    const float* zx = dir ? zx1 : zx0;
    const float* gn = dir ? gn1 : gn0;
    int row = blockIdx.x;
    float g[2]; float ss = 0.f;
    #pragma unroll
    for (int r = 0; r < 2; ++r){
        int c = threadIdx.x + 256 * r;
        float z = zx[(size_t)row * DINPROJ + c];
        float val = y[(size_t)row * DIN + c] * silu_f(z);
        g[r] = val; ss += val * val;
    }
    float tot = block_sum256(ss);
    float sc = rsqrtf(tot / (float)DIN + EPS);
    #pragma unroll
    for (int r = 0; r < 2; ++r){
        int c = threadIdx.x + 256 * r;
        y[(size_t)row * DIN + c] = g[r] * sc * gn[c];
    }
}

// ---------------- rmsnorm over D=256, one row per block
__global__ void rmsnorm256_k(const float* __restrict__ x, const float* __restrict__ w,
                             float* __restrict__ o){
    int row = blockIdx.x;
    float v = x[(size_t)row * D + threadIdx.x];
    float ss = block_sum256(v * v);
    float sc = rsqrtf(ss / (float)D + EPS);
    o[(size_t)row * D + threadIdx.x] = v * sc * w[threadIdx.x];
}

// ---------------- tm[b,d] = mean_l r[b,l,d]
__global__ void mean_l_k(const float* __restrict__ r, float* __restrict__ tm){
    int b = blockIdx.x, d = threadIdx.x;
    float acc = 0.f;
    for (int l = 0; l < L; ++l) acc += r[(size_t)(b * L + l) * D + d];
    tm[b * D + d] = acc * (1.f / (float)L);
}

extern "C" void kernel_launch(void* const* d_in, const int* in_sizes, int n_in,
                              void* d_out, int out_size, void* d_ws, size_t ws_size,
                              hipStream_t stream){
    (void)in_sizes; (void)n_in; (void)out_size; (void)ws_size;
    const float* x       = (const float*)d_in[0];
    const float* patch_w = (const float*)d_in[1];
    const float* patch_b = (const float*)d_in[2];
    const float* pos     = (const float*)d_in[3];
    const float* norms_w = (const float*)d_in[4];
    const float* final_w = (const float*)d_in[5];
    const float* head_w  = (const float*)d_in[6];
    const float* head_b  = (const float*)d_in[7];
    const float* Win[2]  = {(const float*)d_in[8],  (const float*)d_in[16]};
    const float* cw[2]   = {(const float*)d_in[9],  (const float*)d_in[17]};
    const float* cb[2]   = {(const float*)d_in[10], (const float*)d_in[18]};
    const float* dtb[2]  = {(const float*)d_in[11], (const float*)d_in[19]};
    const float* Alog[2] = {(const float*)d_in[12], (const float*)d_in[20]};
    const float* Dp[2]   = {(const float*)d_in[13], (const float*)d_in[21]};
    const float* gn[2]   = {(const float*)d_in[14], (const float*)d_in[22]};
    const float* Wout[2] = {(const float*)d_in[15], (const float*)d_in[23]};

    float* ws  = (float*)d_ws;
    float* p    = ws;                 // B*L*768      = 786432
    float* t    = p    + 786432;      // B*L*D        = 262144
    float* nx   = t    + 262144;      // B*L*D        = 262144
    float* tm   = nx   + 262144;      // B*D          = 4096
    float* zx0  = tm   + 4096;        // B*L*DINPROJ  = 1187840
    float* zx1  = zx0  + 1187840;
    float* xbc0 = zx1  + 1187840;     // B*L*CDIM     = 655360
    float* xbc1 = xbc0 + 655360;
    float* dts0 = xbc1 + 655360;      // B*L*H        = 8192
    float* dts1 = dts0 + 8192;
    float* cum0 = dts1 + 8192;
    float* cum1 = cum0 + 8192;
    float* S0   = cum1 + 8192;        // B*L*L        = 65536
    float* S1   = S0   + 65536;
    float* y0   = S1   + 65536;       // B*L*DIN      = 524288
    float* y1   = y0   + 524288;
    // split-K partial buffer: aliases zx0 (dead at patch / out-proj / head time)
    float* part = zx0;                // needs up to 4*262144 = 1048576 < 1187840

    const int BL = BATCH * L;   // 1024 rows

    // --- patch embedding (snake-ordered): t = p @ patch_w^T + pb + pos ---
    patchify_k<<<dim3(L, BATCH), 256, 0, stream>>>(x, p);
    gemm_dbuf_k<true><<<dim3(4, 16, 4), 256, 0, stream>>>(
        p, p, patch_w, patch_w, part, part, BL, D, 768, 4);
    patch_red_k<<<BL, 256, 0, stream>>>(part, patch_b, pos, t);

    // --- layers ---
    for (int i = 0; i < DEPTH; ++i){
        const float* Wi0  = Win[0]  + (size_t)i * D * DINPROJ;
        const float* Wi1  = Win[1]  + (size_t)i * D * DINPROJ;
        const float* cw0  = cw[0]   + (size_t)i * CDIM * DCONV;
        const float* cw1  = cw[1]   + (size_t)i * CDIM * DCONV;
        const float* cb0  = cb[0]   + (size_t)i * CDIM;
        const float* cb1  = cb[1]   + (size_t)i * CDIM;
        const float* dtb0 = dtb[0]  + (size_t)i * H;
        const float* dtb1 = dtb[1]  + (size_t)i * H;
        const float* Al0  = Alog[0] + (size_t)i * H;
        const float* Al1  = Alog[1] + (size_t)i * H;
        const float* Dp0  = Dp[0]   + (size_t)i * H;
        const float* Dp1  = Dp[1]   + (size_t)i * H;
        const float* gn0  = gn[0]   + (size_t)i * DIN;
        const float* gn1  = gn[1]   + (size_t)i * DIN;
        const float* Wo0  = Wout[0] + (size_t)i * DIN * D;
        const float* Wo1  = Wout[1] + (size_t)i * DIN * D;

        rmsnorm256_k<<<BL, 256, 0, stream>>>(t, norms_w + i * D, nx);
        gemm_dbuf_k<false><<<dim3(19, 16, 2), 256, 0, stream>>>(
            nx, nx, Wi0, Wi1, zx0, zx1, BL, DINPROJ, D, 1);
        dt_scan_k<<<dim3(32, 2), 256, 0, stream>>>(
            zx0, zx1, dtb0, dtb1, Al0, Al1, dts0, dts1, cum0, cum1);
        conv_silu_k<<<dim3(L, BATCH, 2), 256, 0, stream>>>(
            zx0, zx1, cw0, cw1, cb0, cb1, xbc0, xbc1);
        bc_dots_k<<<dim3(BATCH, 2), 256, 0, stream>>>(xbc0, xbc1, S0, S1);
        yscan_k<<<dim3(H, BATCH, 2), 256, 0, stream>>>(
            S0, S1, xbc0, xbc1, dts0, dts1, cum0, cum1, Dp0, Dp1, y0, y1);
        gate_rmsnorm_k<<<dim3(BL, 2), 256, 0, stream>>>(y0, y1, zx0, zx1, gn0, gn1);
        // out-proj: both dirs, split-K 2 -> 4 partial slabs in `part` (zx0 dead now)
        gemm_dbuf_k<false><<<dim3(4, 16, 4), 256, 0, stream>>>(
            y0, y1, Wo0, Wo1, part, part + 2 * 262144, BL, D, DIN, 2);
        out_red_k<<<BL, 256, 0, stream>>>(part, t);
    }

    // --- head ---
    rmsnorm256_k<<<BL, 256, 0, stream>>>(t, final_w, nx);
    mean_l_k<<<BATCH, 256, 0, stream>>>(nx, tm);
    gemm_dbuf_k<false><<<dim3(16, 1, 8), 256, 0, stream>>>(
        tm, tm, head_w, head_w, part, part, BATCH, NCLS, D, 8);
    head_red_k<<<(BATCH * NCLS + 255) / 256, 256, 0, stream>>>(
        part, head_b, (float*)d_out);
}

// Round 3
// 174.013 us; speedup vs baseline: 5.2711x; 2.4918x over previous
//
#include <hip/hip_runtime.h>
#include <hip/hip_bf16.h>
#include <math.h>

#define IMG 128
#define PATCH 16
#define L 64
#define D 256
#define DIN 512
#define DH 64
#define H 8
#define NSTATE 64
#define DCONV 4
#define DEPTH 2
#define NCLS 1000
#define BATCH 16
#define DINPROJ 1160   // 2*DIN + 2*N + H
#define CDIM 640       // DIN + 2*N
#define EPS 1e-6f

typedef __attribute__((ext_vector_type(8))) short short8;
typedef __attribute__((ext_vector_type(4))) float f32x4;
typedef unsigned short ushort_t;

__device__ __forceinline__ int snake_tok(int s){
    int r = s >> 3, c = s & 7;
    return (r & 1) ? (r * 8 + (7 - c)) : (r * 8 + c);
}
__device__ __forceinline__ float silu_f(float x){ return x / (1.f + expf(-x)); }
__device__ __forceinline__ float softplus_f(float x){ return x > 20.f ? x : log1pf(expf(x)); }
__device__ __forceinline__ ushort_t f2b(float f){
    __hip_bfloat16 h = __float2bfloat16(f);
    return *(ushort_t*)&h;
}

__device__ __forceinline__ float block_sum256(float v){
    __shared__ float sm[4];
    #pragma unroll
    for (int o = 32; o > 0; o >>= 1) v += __shfl_down(v, o);
    if ((threadIdx.x & 63) == 0) sm[threadIdx.x >> 6] = v;
    __syncthreads();
    return sm[0] + sm[1] + sm[2] + sm[3];
}

// ---------------- weight convert: Win/Wout transposed to [N][K] bf16; patch_w copied
// wbuf layout (ushort units): pw_bf @0 (196608), win_bf @196608 (4 x 296960, slot=2*layer+dir),
//                             wout_bf @1384448 (4 x 131072, slot=2*layer+dir)
__global__ void wconv_k(const float* __restrict__ Win0, const float* __restrict__ Win1,
                        const float* __restrict__ Wout0, const float* __restrict__ Wout1,
                        const float* __restrict__ pw, ushort_t* __restrict__ wbuf){
    int z = blockIdx.z;
    if (z == 8){
        int id = (blockIdx.y * 37 + blockIdx.x) * 256 + threadIdx.x;
        for (; id < 196608; id += 37 * 16 * 256)
            wbuf[id] = f2b(pw[id]);
        return;
    }
    __shared__ float sm[32][33];
    int R, C; const float* src; ushort_t* dst;
    if (z < 4){
        int layer = z >> 1, dir = z & 1;
        src = (dir ? Win1 : Win0) + (size_t)layer * D * DINPROJ;
        dst = wbuf + 196608 + (size_t)z * 296960;
        R = D; C = DINPROJ;
    } else {
        int zz = z - 4, layer = zz >> 1, dir = zz & 1;
        src = (dir ? Wout1 : Wout0) + (size_t)layer * DIN * D;
        dst = wbuf + 1384448 + (size_t)zz * 131072;
        R = DIN; C = D;
    }
    int ctiles = (C + 31) >> 5, rtiles = R >> 5;
    if (blockIdx.x >= ctiles || blockIdx.y >= rtiles) return;
    int c0 = blockIdx.x * 32, r0 = blockIdx.y * 32;
    int tx = threadIdx.x & 31, ty = threadIdx.x >> 5;
    #pragma unroll
    for (int k = 0; k < 4; ++k){
        int r = r0 + ty + 8 * k, c = c0 + tx;
        sm[ty + 8 * k][tx] = (c < C) ? src[(size_t)r * C + c] : 0.f;
    }
    __syncthreads();
    #pragma unroll
    for (int k = 0; k < 4; ++k){
        int dr = c0 + ty + 8 * k, dc = r0 + tx;
        if (dr < C) dst[(size_t)dr * R + dc] = f2b(sm[tx][ty + 8 * k]);
    }
}

// ---------------- patchify: x (B,3,128,128) -> p_bf (B, L snake, 768) bf16
__global__ void patchify_k(const float* __restrict__ x, ushort_t* __restrict__ p){
    int s = blockIdx.x, b = blockIdx.y;
    int tok = snake_tok(s), gy = tok >> 3, gx = tok & 7;
    const float* xb = x + (size_t)b * 3 * IMG * IMG;
    ushort_t* pr = p + (size_t)(b * L + s) * 768;
    for (int idx = threadIdx.x; idx < 768; idx += blockDim.x){
        int c = idx >> 8, rem = idx & 255, py = rem >> 4, px = rem & 15;
        pr[idx] = f2b(xb[((size_t)c * IMG + gy * PATCH + py) * IMG + gx * PATCH + px]);
    }
}

// ---------------- MFMA bf16 GEMM: C(f32) = A(bf16 [M][K]) @ B(bf16 [N][K])^T
// 64x64 block tile, BK=32, 4 waves as 2x2 of 32x32 wave tiles.
// MODE 0: plain store. MODE 1: +patch_b[n] + pos[snake(m&63)*D+n].
// grid.z = dir selects A0/B0/C0 vs A1/B1/C1.
template<int MODE>
__global__ __launch_bounds__(256) void gemm_mfma_k(
    const ushort_t* __restrict__ A0, const ushort_t* __restrict__ A1,
    const ushort_t* __restrict__ B0, const ushort_t* __restrict__ B1,
    float* __restrict__ C0, float* __restrict__ C1,
    const float* __restrict__ pb, const float* __restrict__ pos,
    int M, int N, int K)
{
    __shared__ __align__(16) ushort_t As[2][64][40];
    __shared__ __align__(16) ushort_t Bs[2][64][40];
    const int dir = blockIdx.z;
    const ushort_t* __restrict__ A = dir ? A1 : A0;
    const ushort_t* __restrict__ B = dir ? B1 : B0;
    float* __restrict__ C = dir ? C1 : C0;
    const int t = threadIdx.x;
    const int n0 = blockIdx.x * 64, m0 = blockIdx.y * 64;
    const int lrow = t >> 2;          // 0..63 tile row
    const int lcol = (t & 3) * 8;     // k offset (8 bf16 = 16B)
    const int wave = t >> 6, lane = t & 63;
    const int wm = (wave >> 1) * 32, wn = (wave & 1) * 32;
    const int fro = lane & 15, fk = (lane >> 4) * 8;

    f32x4 acc[2][2];
    #pragma unroll
    for (int i = 0; i < 2; ++i)
        #pragma unroll
        for (int j = 0; j < 2; ++j)
            acc[i][j] = (f32x4){0.f, 0.f, 0.f, 0.f};

    float4 areg, breg;
    auto gload = [&](int kk){
        areg = *(const float4*)(A + (size_t)(m0 + lrow) * K + kk + lcol);
        int gn = n0 + lrow;
        if (gn < N) breg = *(const float4*)(B + (size_t)gn * K + kk + lcol);
        else        breg = make_float4(0.f, 0.f, 0.f, 0.f);
    };
    auto sstore = [&](int buf){
        *(float4*)&As[buf][lrow][lcol] = areg;
        *(float4*)&Bs[buf][lrow][lcol] = breg;
    };

    const int nk = K / 32;
    gload(0); sstore(0);
    __syncthreads();
    for (int kt = 0; kt < nk; ++kt){
        const int buf = kt & 1;
        if (kt + 1 < nk) gload((kt + 1) * 32);
        short8 af[2], bfr[2];
        af[0]  = *(const short8*)&As[buf][wm + fro][fk];
        af[1]  = *(const short8*)&As[buf][wm + 16 + fro][fk];
        bfr[0] = *(const short8*)&Bs[buf][wn + fro][fk];
        bfr[1] = *(const short8*)&Bs[buf][wn + 16 + fro][fk];
        #pragma unroll
        for (int i = 0; i < 2; ++i)
            #pragma unroll
            for (int j = 0; j < 2; ++j)
                acc[i][j] = __builtin_amdgcn_mfma_f32_16x16x32_bf16(
                    af[i], bfr[j], acc[i][j], 0, 0, 0);
        if (kt + 1 < nk) sstore(buf ^ 1);
        __syncthreads();
    }

    #pragma unroll
    for (int i = 0; i < 2; ++i){
        #pragma unroll
        for (int j = 0; j < 2; ++j){
            int col = n0 + wn + j * 16 + (lane & 15);
            if (col >= N) continue;
            #pragma unroll
            for (int r = 0; r < 4; ++r){
                int row = m0 + wm + i * 16 + (lane >> 4) * 4 + r;
                float v = acc[i][j][r];
                if (MODE == 1)
                    v += pb[col] + pos[snake_tok(row & 63) * D + col];
                C[(size_t)row * N + col] = v;
            }
        }
    }
}

// ---------------- rmsnorm over D=256; BF -> bf16 output, else f32
template<bool BF>
__global__ void rmsnorm256_k(const float* __restrict__ x, const float* __restrict__ w,
                             void* __restrict__ o){
    int row = blockIdx.x;
    float v = x[(size_t)row * D + threadIdx.x];
    float ss = block_sum256(v * v);
    float sc = rsqrtf(ss / (float)D + EPS);
    float r = v * sc * w[threadIdx.x];
    if (BF) ((ushort_t*)o)[(size_t)row * D + threadIdx.x] = f2b(r);
    else    ((float*)o)[(size_t)row * D + threadIdx.x] = r;
}

// ---------------- dt = softplus(...); cum = inclusive scan of -exp(Alog)*dt
__global__ void dt_scan_k(const float* __restrict__ zx0, const float* __restrict__ zx1,
                          const float* __restrict__ dtb0, const float* __restrict__ dtb1,
                          const float* __restrict__ Al0, const float* __restrict__ Al1,
                          float* __restrict__ dts0, float* __restrict__ dts1,
                          float* __restrict__ cums0, float* __restrict__ cums1){
    int dir = blockIdx.y;
    const float* zx  = dir ? zx1  : zx0;
    const float* dtb = dir ? dtb1 : dtb0;
    const float* Al  = dir ? Al1  : Al0;
    float* dts  = dir ? dts1  : dts0;
    float* cums = dir ? cums1 : cums0;
    int wave = threadIdx.x >> 6, lane = threadIdx.x & 63;
    int bh = blockIdx.x * 4 + wave;
    int b = bh >> 3, h = bh & 7;
    int s = lane;
    int l = dir ? (L - 1 - s) : s;
    float xr = zx[(size_t)(b * L + l) * DINPROJ + DIN + CDIM + h] + dtb[h];
    float dt = softplus_f(xr);
    float val = -expf(Al[h]) * dt;
    #pragma unroll
    for (int o = 1; o < 64; o <<= 1){
        float u = __shfl_up(val, o);
        if (lane >= o) val += u;
    }
    dts[(size_t)(b * L + s) * H + h]  = dt;
    cums[(size_t)(b * L + s) * H + h] = val;
}

// ---------------- causal depthwise conv (scan order) + silu; grid (L,B,2)
__global__ void conv_silu_k(const float* __restrict__ zx0, const float* __restrict__ zx1,
                            const float* __restrict__ cw0, const float* __restrict__ cw1,
                            const float* __restrict__ cb0, const float* __restrict__ cb1,
                            float* __restrict__ xbc0, float* __restrict__ xbc1){
    int dir = blockIdx.z;
    const float* zx = dir ? zx1 : zx0;
    const float* cw = dir ? cw1 : cw0;
    const float* cb = dir ? cb1 : cb0;
    float* xbc = dir ? xbc1 : xbc0;
    int s = blockIdx.x, b = blockIdx.y;
    for (int c = threadIdx.x; c < CDIM; c += blockDim.x){
        float acc = cb[c];
        #pragma unroll
        for (int k = 0; k < DCONV; ++k){
            int j = s - (DCONV - 1) + k;
            if (j >= 0){
                int l = dir ? (L - 1 - j) : j;
                acc += cw[c * DCONV + k] * zx[(size_t)(b * L + l) * DINPROJ + DIN + c];
            }
        }
        xbc[(size_t)(b * L + s) * CDIM + c] = silu_f(acc);
    }
}

// ---------------- S[b,s,j] = C[b,s,:] . B[b,j,:]; grid (B, 2)
__global__ __launch_bounds__(256) void bc_dots_k(const float* __restrict__ xbc0,
                                                 const float* __restrict__ xbc1,
                                                 float* __restrict__ S0,
                                                 float* __restrict__ S1){
    int dir = blockIdx.y;
    const float* xbc = dir ? xbc1 : xbc0;
    float* S = dir ? S1 : S0;
    __shared__ float Bl[64][65];
    __shared__ float Cl[64][65];
    int b = blockIdx.x;
    for (int idx = threadIdx.x; idx < 64 * 64; idx += 256){
        int j = idx >> 6, n = idx & 63;
        Bl[j][n] = xbc[(size_t)(b * L + j) * CDIM + DIN + n];
        Cl[j][n] = xbc[(size_t)(b * L + j) * CDIM + DIN + NSTATE + n];
    }
    __syncthreads();
    for (int idx = threadIdx.x; idx < 64 * 64; idx += 256){
        int s = idx >> 6, j = idx & 63;
        float acc = 0.f;
        #pragma unroll
        for (int n = 0; n < 64; ++n) acc += Cl[s][n] * Bl[j][n];
        S[((size_t)b * L + s) * L + j] = acc;
    }
}

// ---------------- Y; grid (H, B, 2)
__global__ __launch_bounds__(256) void yscan_k(const float* __restrict__ S0,
                                               const float* __restrict__ S1,
                                               const float* __restrict__ xbc0,
                                               const float* __restrict__ xbc1,
                                               const float* __restrict__ dts0,
                                               const float* __restrict__ dts1,
                                               const float* __restrict__ cums0,
                                               const float* __restrict__ cums1,
                                               const float* __restrict__ Dp0,
                                               const float* __restrict__ Dp1,
                                               float* __restrict__ y0,
                                               float* __restrict__ y1){
    int dir = blockIdx.z;
    const float* S = dir ? S1 : S0;
    const float* xbc = dir ? xbc1 : xbc0;
    const float* dts = dir ? dts1 : dts0;
    const float* cums = dir ? cums1 : cums0;
    const float* Dp = dir ? Dp1 : Dp0;
    float* y = dir ? y1 : y0;
    __shared__ float Am[64][65];
    __shared__ float Xs[64][65];
    __shared__ float cumS[64], dtS[64];
    int h = blockIdx.x, b = blockIdx.y;
    if (threadIdx.x < 64){
        cumS[threadIdx.x] = cums[(size_t)(b * L + threadIdx.x) * H + h];
        dtS[threadIdx.x]  = dts[(size_t)(b * L + threadIdx.x) * H + h];
    }
    for (int idx = threadIdx.x; idx < 64 * 64; idx += 256){
        int j = idx >> 6, pcol = idx & 63;
        Xs[j][pcol] = xbc[(size_t)(b * L + j) * CDIM + h * DH + pcol];
        Am[j][pcol] = S[((size_t)b * L + j) * L + pcol];
    }
    __syncthreads();
    for (int idx = threadIdx.x; idx < 64 * 64; idx += 256){
        int s = idx >> 6, j = idx & 63;
        float v = 0.f;
        if (j <= s) v = Am[s][j] * expf(cumS[s] - cumS[j]) * dtS[j];
        Am[s][j] = v;
    }
    __syncthreads();
    float dp = Dp[h];
    for (int idx = threadIdx.x; idx < 64 * 64; idx += 256){
        int s = idx >> 6, pcol = idx & 63;
        float acc = dp * Xs[s][pcol];
        #pragma unroll
        for (int j = 0; j < 64; ++j) acc += Am[s][j] * Xs[j][pcol];
        int l = dir ? (L - 1 - s) : s;
        y[(size_t)(b * L + l) * DIN + h * DH + pcol] = acc;
    }
}

// ---------------- ybf = bf16(rmsnorm(y * silu(z), gn)); grid (BL, 2)
__global__ void gate_rmsnorm_k(const float* __restrict__ y0, const float* __restrict__ y1,
                               const float* __restrict__ zx0, const float* __restrict__ zx1,
                               const float* __restrict__ gn0, const float* __restrict__ gn1,
                               ushort_t* __restrict__ ybf0, ushort_t* __restrict__ ybf1){
    int dir = blockIdx.y;
    const float* y = dir ? y1 : y0;
    const float* zx = dir ? zx1 : zx0;
    const float* gn = dir ? gn1 : gn0;
    ushort_t* ybf = dir ? ybf1 : ybf0;
    int row = blockIdx.x;
    float g[2]; float ss = 0.f;
    #pragma unroll
    for (int r = 0; r < 2; ++r){
        int c = threadIdx.x + 256 * r;
        float z = zx[(size_t)row * DINPROJ + c];
        float val = y[(size_t)row * DIN + c] * silu_f(z);
        g[r] = val; ss += val * val;
    }
    float tot = block_sum256(ss);
    float sc = rsqrtf(tot / (float)DIN + EPS);
    #pragma unroll
    for (int r = 0; r < 2; ++r){
        int c = threadIdx.x + 256 * r;
        ybf[(size_t)row * DIN + c] = f2b(g[r] * sc * gn[c]);
    }
}

// ---------------- t[i] += 0.5*(part0 + part1)
__global__ void out_red_k(const float* __restrict__ part, float* __restrict__ t){
    int i = blockIdx.x * 256 + threadIdx.x;
    t[i] += 0.5f * (part[i] + part[i + BATCH * L * D]);
}

// ---------------- tm[b,d] = mean_l r[b,l,d]
__global__ void mean_l_k(const float* __restrict__ r, float* __restrict__ tm){
    int b = blockIdx.x, d = threadIdx.x;
    float acc = 0.f;
    for (int l = 0; l < L; ++l) acc += r[(size_t)(b * L + l) * D + d];
    tm[b * D + d] = acc * (1.f / (float)L);
}

// ---------------- head: out[m,n] = tm[m,:] . head_w[:,n] + hb[n]  (fp32)
__global__ void head_k(const float* __restrict__ tm, const float* __restrict__ hw,
                       const float* __restrict__ hb, float* __restrict__ out){
    int i = blockIdx.x * 256 + threadIdx.x;
    if (i >= BATCH * NCLS) return;
    int m = i / NCLS, n = i - m * NCLS;
    float a0 = 0.f, a1 = 0.f, a2 = 0.f, a3 = 0.f;
    const float* tr = tm + m * D;
    #pragma unroll 4
    for (int k = 0; k < D; k += 4){
        a0 = fmaf(tr[k],     hw[(size_t)k * NCLS + n],       a0);
        a1 = fmaf(tr[k + 1], hw[(size_t)(k + 1) * NCLS + n], a1);
        a2 = fmaf(tr[k + 2], hw[(size_t)(k + 2) * NCLS + n], a2);
        a3 = fmaf(tr[k + 3], hw[(size_t)(k + 3) * NCLS + n], a3);
    }
    out[i] = (a0 + a1) + (a2 + a3) + hb[n];
}

extern "C" void kernel_launch(void* const* d_in, const int* in_sizes, int n_in,
                              void* d_out, int out_size, void* d_ws, size_t ws_size,
                              hipStream_t stream){
    (void)in_sizes; (void)n_in; (void)out_size; (void)ws_size;
    const float* x       = (const float*)d_in[0];
    const float* patch_w = (const float*)d_in[1];
    const float* patch_b = (const float*)d_in[2];
    const float* pos     = (const float*)d_in[3];
    const float* norms_w = (const float*)d_in[4];
    const float* final_w = (const float*)d_in[5];
    const float* head_w  = (const float*)d_in[6];
    const float* head_b  = (const float*)d_in[7];
    const float* Win[2]  = {(const float*)d_in[8],  (const float*)d_in[16]};
    const float* cw[2]   = {(const float*)d_in[9],  (const float*)d_in[17]};
    const float* cb[2]   = {(const float*)d_in[10], (const float*)d_in[18]};
    const float* dtb[2]  = {(const float*)d_in[11], (const float*)d_in[19]};
    const float* Alog[2] = {(const float*)d_in[12], (const float*)d_in[20]};
    const float* Dp[2]   = {(const float*)d_in[13], (const float*)d_in[21]};
    const float* gn[2]   = {(const float*)d_in[14], (const float*)d_in[22]};
    const float* Wout[2] = {(const float*)d_in[15], (const float*)d_in[23]};

    float* ws = (float*)d_ws;
    float* t    = ws;                  // 262144
    float* nx   = t    + 262144;       // 262144 (f32, final-norm path)
    float* tm   = nx   + 262144;       // 4096
    float* zx0  = tm   + 4096;         // 1187840
    float* zx1  = zx0  + 1187840;
    float* xbc0 = zx1  + 1187840;      // 655360
    float* xbc1 = xbc0 + 655360;
    float* dts0 = xbc1 + 655360;       // 8192 x4
    float* dts1 = dts0 + 8192;
    float* cum0 = dts1 + 8192;
    float* cum1 = cum0 + 8192;
    float* S0   = cum1 + 8192;         // 65536 x2
    float* S1   = S0   + 65536;
    float* y0   = S1   + 65536;        // 524288 x2 (f32 scan output)
    float* y1   = y0   + 524288;
    float* part = zx0;                 // out-proj partials alias zx0 (dead then)
    float* f32end = y1 + 524288;

    ushort_t* bfbase = (ushort_t*)f32end;
    ushort_t* p_bf  = bfbase;                    // 786432
    ushort_t* nx_bf = p_bf  + 786432;            // 262144
    ushort_t* ybf0  = nx_bf + 262144;            // 524288
    ushort_t* ybf1  = ybf0  + 524288;            // 524288
    ushort_t* wbuf  = ybf1  + 524288;            // 1908736
    ushort_t* pw_bf   = wbuf;                    // 196608
    ushort_t* win_bf  = wbuf + 196608;           // 4 x 296960
    ushort_t* wout_bf = wbuf + 1384448;          // 4 x 131072

    const int BL = BATCH * L;   // 1024

    // --- weight conversion (every launch; deterministic) ---
    wconv_k<<<dim3(37, 16, 9), 256, 0, stream>>>(
        Win[0], Win[1], Wout[0], Wout[1], patch_w, wbuf);

    // --- patch embedding: t = p_bf @ pw_bf^T + pb + pos (fused epilogue) ---
    patchify_k<<<dim3(L, BATCH), 256, 0, stream>>>(x, p_bf);
    gemm_mfma_k<1><<<dim3(4, 16, 1), 256, 0, stream>>>(
        p_bf, p_bf, pw_bf, pw_bf, t, t, patch_b, pos, BL, D, 768);

    // --- layers ---
    for (int i = 0; i < DEPTH; ++i){
        const float* cw0  = cw[0]   + (size_t)i * CDIM * DCONV;
        const float* cw1  = cw[1]   + (size_t)i * CDIM * DCONV;
        const float* cb0  = cb[0]   + (size_t)i * CDIM;
        const float* cb1  = cb[1]   + (size_t)i * CDIM;
        const float* dtb0 = dtb[0]  + (size_t)i * H;
        const float* dtb1 = dtb[1]  + (size_t)i * H;
        const float* Al0  = Alog[0] + (size_t)i * H;
        const float* Al1  = Alog[1] + (size_t)i * H;
        const float* Dp0  = Dp[0]   + (size_t)i * H;
        const float* Dp1  = Dp[1]   + (size_t)i * H;
        const float* gn0  = gn[0]   + (size_t)i * DIN;
        const float* gn1  = gn[1]   + (size_t)i * DIN;
        const ushort_t* Wi0 = win_bf  + (size_t)(2 * i + 0) * 296960;
        const ushort_t* Wi1 = win_bf  + (size_t)(2 * i + 1) * 296960;
        const ushort_t* Wo0 = wout_bf + (size_t)(2 * i + 0) * 131072;
        const ushort_t* Wo1 = wout_bf + (size_t)(2 * i + 1) * 131072;

        rmsnorm256_k<true><<<BL, 256, 0, stream>>>(t, norms_w + i * D, nx_bf);
        gemm_mfma_k<0><<<dim3(19, 16, 2), 256, 0, stream>>>(
            nx_bf, nx_bf, Wi0, Wi1, zx0, zx1, nullptr, nullptr, BL, DINPROJ, D);
        dt_scan_k<<<dim3(32, 2), 256, 0, stream>>>(
            zx0, zx1, dtb0, dtb1, Al0, Al1, dts0, dts1, cum0, cum1);
        conv_silu_k<<<dim3(L, BATCH, 2), 256, 0, stream>>>(
            zx0, zx1, cw0, cw1, cb0, cb1, xbc0, xbc1);
        bc_dots_k<<<dim3(BATCH, 2), 256, 0, stream>>>(xbc0, xbc1, S0, S1);
        yscan_k<<<dim3(H, BATCH, 2), 256, 0, stream>>>(
            S0, S1, xbc0, xbc1, dts0, dts1, cum0, cum1, Dp0, Dp1, y0, y1);
        gate_rmsnorm_k<<<dim3(BL, 2), 256, 0, stream>>>(
            y0, y1, zx0, zx1, gn0, gn1, ybf0, ybf1);
        gemm_mfma_k<0><<<dim3(4, 16, 2), 256, 0, stream>>>(
            ybf0, ybf1, Wo0, Wo1, part, part + 262144, nullptr, nullptr, BL, D, DIN);
        out_red_k<<<BL, 256, 0, stream>>>(part, t);
    }

    // --- head (fp32 for final-output precision) ---
    rmsnorm256_k<false><<<BL, 256, 0, stream>>>(t, final_w, nx);
    mean_l_k<<<BATCH, 256, 0, stream>>>(nx, tm);
    head_k<<<(BATCH * NCLS + 255) / 256, 256, 0, stream>>>(
        tm, head_w, head_b, (float*)d_out);
}